// Round 6
// baseline (868.665 us; speedup 1.0000x reference)
//
#include <hip/hip_runtime.h>
#include <cstddef>

#define BT    8192
#define HD    2048
#define NS    32
#define RDIM  16
#define AD    32
#define CAPL  448            // per (slot,schema) list cap; lambda=256, sigma~15.7 -> +12 sigma
#define NLIST 64

// ---------------- workspace layout (bytes) ----------------
// 0         int   cnt[64]                         (pad to 1024)
// 1024      int   tok_list[64][448]               114688
// 115712    float cf_list[64][448]                114688
// 230400    float UT[32][16][2048]                4 MB
// 4424704   float aw[32]                          (pad to 256)
// 4424960   union { float sc_part[4][8192][32];   4 MB   (router -> tail)
//                   float y_part[2][64][448][16]; 3.6 MB } (A -> B; stream-ordered)

__device__ __forceinline__ float dot4(const float4 a, const float4 b) {
    return a.x * b.x + a.y * b.y + a.z * b.z + a.w * b.w;
}
__device__ __forceinline__ void fma4(float4& o, const float a, const float4 b) {
    o.x += a * b.x; o.y += a * b.y; o.z += a * b.z; o.w += a * b.w;
}

// ---------------- prep: zero counters + transpose U + aw = sigmoid(attr@Wa) ----------------
__global__ __launch_bounds__(256) void k_prep(const float* __restrict__ U,
                                              const float* __restrict__ attr,
                                              const float* __restrict__ Wa,
                                              int* __restrict__ cnt,
                                              float* __restrict__ UT,
                                              float* __restrict__ aw) {
    const int bx = blockIdx.x;
    if (bx == NS * 8) {
        if (threadIdx.x < NLIST) cnt[threadIdx.x] = 0;
        if (threadIdx.x >= 64 && threadIdx.x < 64 + NS) {
            const int s = threadIdx.x - 64;
            float sum = 0.f;
            #pragma unroll 1
            for (int d = 0; d < AD; ++d) sum += attr[s * AD + d] * Wa[d];
            aw[s] = 1.f / (1.f + __expf(-sum));
        }
        return;
    }
    const int s = bx >> 3, jc = bx & 7;
    const int j = jc * 256 + threadIdx.x;
    const float4* Up = (const float4*)(U + ((size_t)s * HD + j) * RDIM);
    const float4 a = Up[0], b = Up[1], c = Up[2], d = Up[3];
    float* Tp = UT + (size_t)s * RDIM * HD + j;
    Tp[0]       = a.x; Tp[HD]      = a.y; Tp[2*HD]   = a.z; Tp[3*HD]   = a.w;
    Tp[4*HD]    = b.x; Tp[5*HD]    = b.y; Tp[6*HD]   = b.z; Tp[7*HD]   = b.w;
    Tp[8*HD]    = c.x; Tp[9*HD]    = c.y; Tp[10*HD]  = c.z; Tp[11*HD]  = c.w;
    Tp[12*HD]   = d.x; Tp[13*HD]   = d.y; Tp[14*HD]  = d.z; Tp[15*HD]  = d.w;
}

// ---------------- router: block = (64-token group, 512-dim slice) ----------------
// Stage Wr[32 sch][512 dims] (64 KB) ONCE, one barrier; 8 waves free-run.
// Per iter: 2 tokens, 8 dims/lane (2 c2-steps) into acc[64], ONE butterfly
// (2x amortization vs r5 -> butterfly overhead ~45% -> ~27% of VALU).
__global__ __launch_bounds__(512) void k_router(
    const float* __restrict__ h, const float* __restrict__ Wr,
    float* __restrict__ sc_part)
{
    __shared__ __align__(16) float wst[NS * 512];     // 64 KB
    const int tid = threadIdx.x, w = tid >> 6, lane = tid & 63;
    const int tg = blockIdx.x, cs = blockIdx.y;
    float4* const wst4 = (float4*)wst;

    #pragma unroll
    for (int j = 0; j < 8; ++j) {
        const int f = tid + j * 512;
        const int s = f >> 7, e = f & 127;
        wst4[f] = *((const float4*)(Wr + (size_t)s * HD + cs * 512) + e);
    }
    __syncthreads();   // the only barrier

    #pragma unroll 1
    for (int it = 0; it < 4; ++it) {
        const int ta = tg * 64 + it * 16 + w * 2;

        float acc[64];
        #pragma unroll
        for (int m = 0; m < 64; ++m) acc[m] = 0.f;

        #pragma unroll
        for (int c2 = 0; c2 < 2; ++c2) {
            const float4 h0 = *(const float4*)(h + (size_t)ta * HD + cs * 512 + c2 * 256 + lane * 4);
            const float4 h1 = *(const float4*)(h + (size_t)(ta + 1) * HD + cs * 512 + c2 * 256 + lane * 4);
            #pragma unroll
            for (int s = 0; s < 32; ++s) {
                const float4 wv = wst4[s * 128 + c2 * 64 + lane];
                acc[s]      += dot4(h0, wv);
                acc[32 + s] += dot4(h1, wv);
            }
        }
        // butterfly reduce 64 vals over 64 lanes: lane L ends with m=L (t=L>>5, s=L&31)
        #pragma unroll
        for (int st = 0; st < 6; ++st) {
            const int d = 1 << st;
            const bool up = (lane & d) != 0;
            const int half = 32 >> st;
            #pragma unroll
            for (int i = 0; i < half; ++i) {
                const float lo = acc[2 * i], hi = acc[2 * i + 1];
                const float keep = up ? hi : lo, send = up ? lo : hi;
                acc[i] = keep + __shfl_xor(send, d, 64);
            }
        }
        sc_part[((size_t)cs * BT + ta + (lane >> 5)) * NS + (lane & 31)] = acc[0];
    }
}

// ---------------- tail: thread-per-token sum 4 slices + top-2 / softmax / lists ----------------
__global__ __launch_bounds__(256) void k_tail(
    const float* __restrict__ sc_part, const float* __restrict__ aw,
    int* __restrict__ cnt, int* __restrict__ tok_list, float* __restrict__ cf_list)
{
    const int t = blockIdx.x * 256 + threadIdx.x;
    float s[32];
    #pragma unroll
    for (int k = 0; k < 32; ++k) s[k] = 0.f;
    #pragma unroll 1
    for (int cs = 0; cs < 4; ++cs) {
        const float4* sp = (const float4*)(sc_part + ((size_t)cs * BT + t) * NS);
        #pragma unroll
        for (int j = 0; j < 8; ++j) {
            const float4 v = sp[j];
            s[4*j] += v.x; s[4*j+1] += v.y; s[4*j+2] += v.z; s[4*j+3] += v.w;
        }
    }
    float m1 = -1e30f, m2 = -1e30f;
    int i1 = 0, i2 = 0;
    #pragma unroll
    for (int k = 0; k < 32; ++k) {   // strict > keeps lowest index on ties (lax.top_k)
        const float v = s[k];
        if (v > m1) { m2 = m1; i2 = i1; m1 = v; i1 = k; }
        else if (v > m2) { m2 = v; i2 = k; }
    }
    float Z = 0.f;
    #pragma unroll
    for (int k = 0; k < 32; ++k) Z += __expf(s[k] - m1);
    const float e2  = __expf(m2 - m1);
    // g = softmax(sc)*mask renormed by (sum + 1e-8): G_i = e_i / (e1+e2 + 1e-8*Z)
    const float den = 1.f + e2 + 1e-8f * Z;
    const float G1 = 1.f / den, G2 = e2 / den;
    const float mult = 0.9f + 0.2f * (G1 * aw[i1] + G2 * aw[i2]);
    const float c1 = G1 * mult, c2 = G2 * mult;
    int p = atomicAdd(cnt + i1, 1);
    if (p < CAPL) { tok_list[i1 * CAPL + p] = t; cf_list[i1 * CAPL + p] = c1; }
    p = atomicAdd(cnt + NS + i2, 1);
    if (p < CAPL) { tok_list[(NS + i2) * CAPL + p] = t; cf_list[(NS + i2) * CAPL + p] = c2; }
}

// ---------------- pass A: block = (list g, 1024-dim half cq, 64-token chunk z) ----------------
// Stage UT[s][16 k][half] (64 KB) ONCE, one barrier; waves free-run 4 tok/iter:
// 16 dims/lane (4 c2-steps, h-regs reused per step) into acc[64], ONE butterfly
// (2x amortization vs r5). Partial y per half; k_B sums the 2 halves.
__global__ __launch_bounds__(512) void k_A(
    const float* __restrict__ h, const int* __restrict__ cnt,
    const int* __restrict__ tok_list, const float* __restrict__ cf_list,
    const float* __restrict__ UT, float* __restrict__ y_part)
{
    __shared__ __align__(16) float ust[RDIM * 1024];   // 64 KB
    const int g = blockIdx.x, s = g & (NS - 1), cq = blockIdx.y;
    int count = cnt[g]; if (count > CAPL) count = CAPL;
    const int start = blockIdx.z * 64;
    if (start >= count) return;
    const int end = (start + 64 < count) ? start + 64 : count;
    const int tid = threadIdx.x, w = tid >> 6, lane = tid & 63;
    const float* UTs = UT + (size_t)s * RDIM * HD;
    float4* const ust4 = (float4*)ust;

    #pragma unroll
    for (int j = 0; j < 8; ++j) {
        const int f = tid + j * 512;
        const int k = f >> 8, e = f & 255;
        ust4[f] = *((const float4*)(UTs + (size_t)k * HD + cq * 1024) + e);
    }
    __syncthreads();   // the only barrier

    #pragma unroll 1
    for (int idx0 = start + w * 4; idx0 < end; idx0 += 32) {
        int tok[4]; float cf[4];
        #pragma unroll
        for (int r = 0; r < 4; ++r) {
            const int idx = idx0 + r;
            const bool vld = idx < end;
            tok[r] = vld ? tok_list[g * CAPL + idx] : 0;
            cf[r]  = vld ? cf_list[g * CAPL + idx] : 0.f;
        }

        float acc[64];
        #pragma unroll
        for (int m = 0; m < 64; ++m) acc[m] = 0.f;

        #pragma unroll
        for (int c2 = 0; c2 < 4; ++c2) {
            float4 hv[4];
            #pragma unroll
            for (int r = 0; r < 4; ++r)
                hv[r] = *(const float4*)(h + (size_t)tok[r] * HD + cq * 1024 + c2 * 256 + lane * 4);
            #pragma unroll
            for (int k = 0; k < 16; ++k) {
                const float4 uv = ust4[k * 256 + c2 * 64 + lane];
                #pragma unroll
                for (int r = 0; r < 4; ++r)
                    acc[r * 16 + k] += dot4(hv[r], uv);
            }
        }

        // butterfly reduce: lane L ends holding value m=L (r = L>>4, k = L&15)
        #pragma unroll
        for (int st = 0; st < 6; ++st) {
            const int d = 1 << st;
            const bool up = (lane & d) != 0;
            const int half = 32 >> st;
            #pragma unroll
            for (int i = 0; i < half; ++i) {
                const float lo = acc[2 * i], hi = acc[2 * i + 1];
                const float keep = up ? hi : lo, send = up ? lo : hi;
                acc[i] = keep + __shfl_xor(send, d, 64);
            }
        }
        const int rr = lane >> 4;
        const float cfv = rr == 0 ? cf[0] : rr == 1 ? cf[1] : rr == 2 ? cf[2] : cf[3];
        y_part[((size_t)(cq * NLIST + g) * CAPL + idx0) * 16 + lane] = acc[0] * cfv;
    }
}

// ---------------- pass B: SINGLE launch, both slots; out pre-zeroed, atomic adds ----------------
// Block = (list g 0..63, 1024-dim half cs, 112-token chunk z). Stage V[sch][16 k][half]
// (64 KB) ONCE; waves free-run 4 tok/iter: sum the 2 y halves, broadcast via
// wave-private LDS, 4 c2-steps of 64 fma4, global_atomic_add_f32 into zeroed out.
// Each out dword receives exactly 2 adds (slot0+slot1); f32 add commutes -> exact.
__global__ __launch_bounds__(512) void k_B(
    const float* __restrict__ V, const int* __restrict__ cnt,
    const int* __restrict__ tok_list, const float* __restrict__ y_part,
    float* __restrict__ out)
{
    __shared__ __align__(16) float vst[RDIM * 1024];   // 64 KB
    __shared__ __align__(16) float yld[8 * 64];        // 2 KB, wave-private regions
    const int g = blockIdx.x, sch = g & (NS - 1), cs = blockIdx.y;
    int count = cnt[g]; if (count > CAPL) count = CAPL;
    const int start = blockIdx.z * 112;
    if (start >= count) return;
    const int end = (start + 112 < count) ? start + 112 : count;
    const int tid = threadIdx.x, w = tid >> 6, lane = tid & 63;
    const float* Vs = V + (size_t)sch * RDIM * HD;
    float4* const vst4 = (float4*)vst;
    float4* const yld4 = (float4*)yld;

    #pragma unroll
    for (int j = 0; j < 8; ++j) {
        const int f = tid + j * 512;
        const int k = f >> 8, e = f & 255;
        vst4[f] = *((const float4*)(Vs + (size_t)k * HD + cs * 1024) + e);
    }
    __syncthreads();   // the only barrier

    #pragma unroll 1
    for (int idx0 = start + w * 4; idx0 < end; idx0 += 32) {
        int tok[4]; bool act[4];
        #pragma unroll
        for (int r = 0; r < 4; ++r) {
            const int idx = idx0 + r;
            act[r] = idx < end;
            tok[r] = act[r] ? tok_list[g * CAPL + idx] : 0;
        }

        // lane L: token r=L>>4, k=L&15; sum the 2 dim-half partials
        const float ysum =
            y_part[((size_t)(0 * NLIST + g) * CAPL + idx0) * 16 + lane] +
            y_part[((size_t)(1 * NLIST + g) * CAPL + idx0) * 16 + lane];
        yld[w * 64 + lane] = ysum;   // wave-private: no barrier needed

        #pragma unroll
        for (int c2 = 0; c2 < 4; ++c2) {
            float4 o[4];
            #pragma unroll
            for (int r = 0; r < 4; ++r) o[r] = make_float4(0.f, 0.f, 0.f, 0.f);

            #pragma unroll
            for (int kg = 0; kg < 4; ++kg) {
                float4 vv[4];
                #pragma unroll
                for (int q = 0; q < 4; ++q)
                    vv[q] = vst4[(kg * 4 + q) * 256 + c2 * 64 + lane];
                #pragma unroll
                for (int r = 0; r < 4; ++r) {
                    const float4 yv = yld4[w * 16 + r * 4 + kg];   // broadcast read
                    fma4(o[r], yv.x, vv[0]); fma4(o[r], yv.y, vv[1]);
                    fma4(o[r], yv.z, vv[2]); fma4(o[r], yv.w, vv[3]);
                }
            }
            #pragma unroll
            for (int r = 0; r < 4; ++r) {
                if (act[r]) {
                    float* op = out + (size_t)tok[r] * HD + cs * 1024 + c2 * 256 + lane * 4;
                    atomicAdd(op + 0, o[r].x);
                    atomicAdd(op + 1, o[r].y);
                    atomicAdd(op + 2, o[r].z);
                    atomicAdd(op + 3, o[r].w);
                }
            }
        }
    }
}

extern "C" void kernel_launch(void* const* d_in, const int* in_sizes, int n_in,
                              void* d_out, int out_size, void* d_ws, size_t ws_size,
                              hipStream_t stream)
{
    const float* h    = (const float*)d_in[0];
    const float* Wr   = (const float*)d_in[1];
    const float* U    = (const float*)d_in[2];
    const float* V    = (const float*)d_in[3];
    const float* attr = (const float*)d_in[4];
    const float* Wa   = (const float*)d_in[5];
    float* outp = (float*)d_out;

    char* ws = (char*)d_ws;
    int*   cnt      = (int*)ws;
    int*   tok_list = (int*)(ws + 1024);
    float* cf_list  = (float*)(ws + 1024 + (size_t)NLIST * CAPL * 4);
    float* UT       = (float*)(ws + 1024 + (size_t)2 * NLIST * CAPL * 4);
    float* aw       = UT + (size_t)NS * RDIM * HD;
    float* big      = aw + 64;                       // sc_part / y_part union
    float* sc_part  = big;
    float* y_part   = big;

    hipMemsetAsync(outp, 0, (size_t)out_size, stream);   // zero out for atomic accumulation
    hipLaunchKernelGGL(k_prep,   dim3(NS * 8 + 1), dim3(256), 0, stream,
                       U, attr, Wa, cnt, UT, aw);
    hipLaunchKernelGGL(k_router, dim3(BT / 64, 4), dim3(512), 0, stream, h, Wr, sc_part);
    hipLaunchKernelGGL(k_tail,   dim3(BT / 256),   dim3(256), 0, stream,
                       sc_part, aw, cnt, tok_list, cf_list);
    hipLaunchKernelGGL(k_A,      dim3(NLIST, 2, 7), dim3(512), 0, stream,
                       h, cnt, tok_list, cf_list, UT, y_part);
    hipLaunchKernelGGL(k_B,      dim3(NLIST, 2, 4), dim3(512), 0, stream,
                       V, cnt, tok_list, y_part, outp);
}

// Round 7
// 472.327 us; speedup vs baseline: 1.8391x; 1.8391x over previous
//
#include <hip/hip_runtime.h>
#include <cstddef>

#define BT    8192
#define HD    2048
#define NS    32
#define RDIM  16
#define AD    32
#define CAPL  448            // per (slot,schema) list cap; lambda=256, sigma~15.7 -> +12 sigma
#define NLIST 64

// ---------------- workspace layout (bytes) ----------------
// 0         int   cnt[64]                         (pad to 1024)
// 1024      int   tok_list[64][448]               114688
// 115712    float cf_list[64][448]                114688
// 230400    float UT[32][16][2048]                4 MB
// 4424704   float aw[32]                          (pad to 256)
// 4424960   union { float sc_part[4][8192][32];   4 MB   (router -> tail)
//                   float y_part[2][64][448][16]; 3.6 MB } (A -> B; stream-ordered)

__device__ __forceinline__ float dot4(const float4 a, const float4 b) {
    return a.x * b.x + a.y * b.y + a.z * b.z + a.w * b.w;
}
__device__ __forceinline__ void fma4(float4& o, const float a, const float4 b) {
    o.x += a * b.x; o.y += a * b.y; o.z += a * b.z; o.w += a * b.w;
}

// ---------------- prep: zero counters + transpose U + aw = sigmoid(attr@Wa) ----------------
__global__ __launch_bounds__(256) void k_prep(const float* __restrict__ U,
                                              const float* __restrict__ attr,
                                              const float* __restrict__ Wa,
                                              int* __restrict__ cnt,
                                              float* __restrict__ UT,
                                              float* __restrict__ aw) {
    const int bx = blockIdx.x;
    if (bx == NS * 8) {
        if (threadIdx.x < NLIST) cnt[threadIdx.x] = 0;
        if (threadIdx.x >= 64 && threadIdx.x < 64 + NS) {
            const int s = threadIdx.x - 64;
            float sum = 0.f;
            #pragma unroll 1
            for (int d = 0; d < AD; ++d) sum += attr[s * AD + d] * Wa[d];
            aw[s] = 1.f / (1.f + __expf(-sum));
        }
        return;
    }
    const int s = bx >> 3, jc = bx & 7;
    const int j = jc * 256 + threadIdx.x;
    const float4* Up = (const float4*)(U + ((size_t)s * HD + j) * RDIM);
    const float4 a = Up[0], b = Up[1], c = Up[2], d = Up[3];
    float* Tp = UT + (size_t)s * RDIM * HD + j;
    Tp[0]       = a.x; Tp[HD]      = a.y; Tp[2*HD]   = a.z; Tp[3*HD]   = a.w;
    Tp[4*HD]    = b.x; Tp[5*HD]    = b.y; Tp[6*HD]   = b.z; Tp[7*HD]   = b.w;
    Tp[8*HD]    = c.x; Tp[9*HD]    = c.y; Tp[10*HD]  = c.z; Tp[11*HD]  = c.w;
    Tp[12*HD]   = d.x; Tp[13*HD]   = d.y; Tp[14*HD]  = d.z; Tp[15*HD]  = d.w;
}

// ---------------- router: block = (64-token group, 512-dim slice) ----------------
// Stage Wr[32 sch][512 dims] (64 KB) ONCE, one barrier; 8 waves free-run.
// Per iter: 2 tokens, 8 dims/lane (2 c2-steps) into acc[64], ONE butterfly.
__global__ __launch_bounds__(512) void k_router(
    const float* __restrict__ h, const float* __restrict__ Wr,
    float* __restrict__ sc_part)
{
    __shared__ __align__(16) float wst[NS * 512];     // 64 KB
    const int tid = threadIdx.x, w = tid >> 6, lane = tid & 63;
    const int tg = blockIdx.x, cs = blockIdx.y;
    float4* const wst4 = (float4*)wst;

    #pragma unroll
    for (int j = 0; j < 8; ++j) {
        const int f = tid + j * 512;
        const int s = f >> 7, e = f & 127;
        wst4[f] = *((const float4*)(Wr + (size_t)s * HD + cs * 512) + e);
    }
    __syncthreads();   // the only barrier

    #pragma unroll 1
    for (int it = 0; it < 4; ++it) {
        const int ta = tg * 64 + it * 16 + w * 2;

        float acc[64];
        #pragma unroll
        for (int m = 0; m < 64; ++m) acc[m] = 0.f;

        #pragma unroll
        for (int c2 = 0; c2 < 2; ++c2) {
            const float4 h0 = *(const float4*)(h + (size_t)ta * HD + cs * 512 + c2 * 256 + lane * 4);
            const float4 h1 = *(const float4*)(h + (size_t)(ta + 1) * HD + cs * 512 + c2 * 256 + lane * 4);
            #pragma unroll
            for (int s = 0; s < 32; ++s) {
                const float4 wv = wst4[s * 128 + c2 * 64 + lane];
                acc[s]      += dot4(h0, wv);
                acc[32 + s] += dot4(h1, wv);
            }
        }
        // butterfly reduce 64 vals over 64 lanes: lane L ends with m=L (t=L>>5, s=L&31)
        #pragma unroll
        for (int st = 0; st < 6; ++st) {
            const int d = 1 << st;
            const bool up = (lane & d) != 0;
            const int half = 32 >> st;
            #pragma unroll
            for (int i = 0; i < half; ++i) {
                const float lo = acc[2 * i], hi = acc[2 * i + 1];
                const float keep = up ? hi : lo, send = up ? lo : hi;
                acc[i] = keep + __shfl_xor(send, d, 64);
            }
        }
        sc_part[((size_t)cs * BT + ta + (lane >> 5)) * NS + (lane & 31)] = acc[0];
    }
}

// ---------------- tail: thread-per-token sum 4 slices + top-2 / softmax / lists ----------------
__global__ __launch_bounds__(256) void k_tail(
    const float* __restrict__ sc_part, const float* __restrict__ aw,
    int* __restrict__ cnt, int* __restrict__ tok_list, float* __restrict__ cf_list)
{
    const int t = blockIdx.x * 256 + threadIdx.x;
    float s[32];
    #pragma unroll
    for (int k = 0; k < 32; ++k) s[k] = 0.f;
    #pragma unroll 1
    for (int cs = 0; cs < 4; ++cs) {
        const float4* sp = (const float4*)(sc_part + ((size_t)cs * BT + t) * NS);
        #pragma unroll
        for (int j = 0; j < 8; ++j) {
            const float4 v = sp[j];
            s[4*j] += v.x; s[4*j+1] += v.y; s[4*j+2] += v.z; s[4*j+3] += v.w;
        }
    }
    float m1 = -1e30f, m2 = -1e30f;
    int i1 = 0, i2 = 0;
    #pragma unroll
    for (int k = 0; k < 32; ++k) {   // strict > keeps lowest index on ties (lax.top_k)
        const float v = s[k];
        if (v > m1) { m2 = m1; i2 = i1; m1 = v; i1 = k; }
        else if (v > m2) { m2 = v; i2 = k; }
    }
    float Z = 0.f;
    #pragma unroll
    for (int k = 0; k < 32; ++k) Z += __expf(s[k] - m1);
    const float e2  = __expf(m2 - m1);
    // g = softmax(sc)*mask renormed by (sum + 1e-8): G_i = e_i / (e1+e2 + 1e-8*Z)
    const float den = 1.f + e2 + 1e-8f * Z;
    const float G1 = 1.f / den, G2 = e2 / den;
    const float mult = 0.9f + 0.2f * (G1 * aw[i1] + G2 * aw[i2]);
    const float c1 = G1 * mult, c2 = G2 * mult;
    int p = atomicAdd(cnt + i1, 1);
    if (p < CAPL) { tok_list[i1 * CAPL + p] = t; cf_list[i1 * CAPL + p] = c1; }
    p = atomicAdd(cnt + NS + i2, 1);
    if (p < CAPL) { tok_list[(NS + i2) * CAPL + p] = t; cf_list[(NS + i2) * CAPL + p] = c2; }
}

// ---------------- pass A: block = (list g, 1024-dim half cq, 64-token chunk z) ----------------
// Stage UT[s][16 k][half] (64 KB) ONCE, one barrier; waves free-run 4 tok/iter:
// 16 dims/lane (4 c2-steps) into acc[64], ONE butterfly. k_B sums the 2 halves.
__global__ __launch_bounds__(512) void k_A(
    const float* __restrict__ h, const int* __restrict__ cnt,
    const int* __restrict__ tok_list, const float* __restrict__ cf_list,
    const float* __restrict__ UT, float* __restrict__ y_part)
{
    __shared__ __align__(16) float ust[RDIM * 1024];   // 64 KB
    const int g = blockIdx.x, s = g & (NS - 1), cq = blockIdx.y;
    int count = cnt[g]; if (count > CAPL) count = CAPL;
    const int start = blockIdx.z * 64;
    if (start >= count) return;
    const int end = (start + 64 < count) ? start + 64 : count;
    const int tid = threadIdx.x, w = tid >> 6, lane = tid & 63;
    const float* UTs = UT + (size_t)s * RDIM * HD;
    float4* const ust4 = (float4*)ust;

    #pragma unroll
    for (int j = 0; j < 8; ++j) {
        const int f = tid + j * 512;
        const int k = f >> 8, e = f & 255;
        ust4[f] = *((const float4*)(UTs + (size_t)k * HD + cq * 1024) + e);
    }
    __syncthreads();   // the only barrier

    #pragma unroll 1
    for (int idx0 = start + w * 4; idx0 < end; idx0 += 32) {
        int tok[4]; float cf[4];
        #pragma unroll
        for (int r = 0; r < 4; ++r) {
            const int idx = idx0 + r;
            const bool vld = idx < end;
            tok[r] = vld ? tok_list[g * CAPL + idx] : 0;
            cf[r]  = vld ? cf_list[g * CAPL + idx] : 0.f;
        }

        float acc[64];
        #pragma unroll
        for (int m = 0; m < 64; ++m) acc[m] = 0.f;

        #pragma unroll
        for (int c2 = 0; c2 < 4; ++c2) {
            float4 hv[4];
            #pragma unroll
            for (int r = 0; r < 4; ++r)
                hv[r] = *(const float4*)(h + (size_t)tok[r] * HD + cq * 1024 + c2 * 256 + lane * 4);
            #pragma unroll
            for (int k = 0; k < 16; ++k) {
                const float4 uv = ust4[k * 256 + c2 * 64 + lane];
                #pragma unroll
                for (int r = 0; r < 4; ++r)
                    acc[r * 16 + k] += dot4(hv[r], uv);
            }
        }

        // butterfly reduce: lane L ends holding value m=L (r = L>>4, k = L&15)
        #pragma unroll
        for (int st = 0; st < 6; ++st) {
            const int d = 1 << st;
            const bool up = (lane & d) != 0;
            const int half = 32 >> st;
            #pragma unroll
            for (int i = 0; i < half; ++i) {
                const float lo = acc[2 * i], hi = acc[2 * i + 1];
                const float keep = up ? hi : lo, send = up ? lo : hi;
                acc[i] = keep + __shfl_xor(send, d, 64);
            }
        }
        const int rr = lane >> 4;
        const float cfv = rr == 0 ? cf[0] : rr == 1 ? cf[1] : rr == 2 ? cf[2] : cf[3];
        y_part[((size_t)(cq * NLIST + g) * CAPL + idx0) * 16 + lane] = acc[0] * cfv;
    }
}

// ---------------- pass B: two launches (slot 0 store, slot 1 RMW); coalesced float4 IO ----------------
// Block = (schema, 1024-dim half cs, token chunk z). Stage V[sch][16 k][half] (64 KB)
// ONCE; waves free-run 4 tok/iter: sum the 2 y halves, broadcast via wave-private
// LDS, 4 c2-steps of 64 fma4, float4 store (slot 0) or non-atomic RMW add (slot 1;
// separate launch -> ordered, race-free: each token appears once per slot's lists).
__global__ __launch_bounds__(512) void k_B(
    const float* __restrict__ V, const int* __restrict__ cnt,
    const int* __restrict__ tok_list, const float* __restrict__ y_part,
    float* __restrict__ out, const int slot)
{
    __shared__ __align__(16) float vst[RDIM * 1024];   // 64 KB
    __shared__ __align__(16) float yld[8 * 64];        // 2 KB, wave-private regions
    const int sch = blockIdx.x, cs = blockIdx.y;
    const int g = slot * NS + sch;
    int count = cnt[g]; if (count > CAPL) count = CAPL;
    const int start = blockIdx.z * 112;
    if (start >= count) return;
    const int end = (start + 112 < count) ? start + 112 : count;
    const int tid = threadIdx.x, w = tid >> 6, lane = tid & 63;
    const float* Vs = V + (size_t)sch * RDIM * HD;
    float4* const vst4 = (float4*)vst;
    float4* const yld4 = (float4*)yld;

    #pragma unroll
    for (int j = 0; j < 8; ++j) {
        const int f = tid + j * 512;
        const int k = f >> 8, e = f & 255;
        vst4[f] = *((const float4*)(Vs + (size_t)k * HD + cs * 1024) + e);
    }
    __syncthreads();   // the only barrier

    #pragma unroll 1
    for (int idx0 = start + w * 4; idx0 < end; idx0 += 32) {
        int tok[4]; bool act[4];
        #pragma unroll
        for (int r = 0; r < 4; ++r) {
            const int idx = idx0 + r;
            act[r] = idx < end;
            tok[r] = act[r] ? tok_list[g * CAPL + idx] : 0;
        }

        // lane L: token r=L>>4, k=L&15; sum the 2 dim-half partials
        const float ysum =
            y_part[((size_t)(0 * NLIST + g) * CAPL + idx0) * 16 + lane] +
            y_part[((size_t)(1 * NLIST + g) * CAPL + idx0) * 16 + lane];
        yld[w * 64 + lane] = ysum;   // wave-private: no barrier needed

        #pragma unroll
        for (int c2 = 0; c2 < 4; ++c2) {
            float4 ov[4];
            if (slot) {
                #pragma unroll
                for (int r = 0; r < 4; ++r)
                    if (act[r]) ov[r] = *(const float4*)(out + (size_t)tok[r] * HD + cs * 1024 + c2 * 256 + lane * 4);
            }
            float4 o[4];
            #pragma unroll
            for (int r = 0; r < 4; ++r) o[r] = make_float4(0.f, 0.f, 0.f, 0.f);

            #pragma unroll
            for (int kg = 0; kg < 4; ++kg) {
                float4 vv[4];
                #pragma unroll
                for (int q = 0; q < 4; ++q)
                    vv[q] = vst4[(kg * 4 + q) * 256 + c2 * 64 + lane];
                #pragma unroll
                for (int r = 0; r < 4; ++r) {
                    const float4 yv = yld4[w * 16 + r * 4 + kg];   // broadcast read
                    fma4(o[r], yv.x, vv[0]); fma4(o[r], yv.y, vv[1]);
                    fma4(o[r], yv.z, vv[2]); fma4(o[r], yv.w, vv[3]);
                }
            }
            #pragma unroll
            for (int r = 0; r < 4; ++r) {
                if (act[r]) {
                    float* op = out + (size_t)tok[r] * HD + cs * 1024 + c2 * 256 + lane * 4;
                    if (slot) {
                        o[r].x += ov[r].x; o[r].y += ov[r].y;
                        o[r].z += ov[r].z; o[r].w += ov[r].w;
                    }
                    *(float4*)op = o[r];
                }
            }
        }
    }
}

extern "C" void kernel_launch(void* const* d_in, const int* in_sizes, int n_in,
                              void* d_out, int out_size, void* d_ws, size_t ws_size,
                              hipStream_t stream)
{
    const float* h    = (const float*)d_in[0];
    const float* Wr   = (const float*)d_in[1];
    const float* U    = (const float*)d_in[2];
    const float* V    = (const float*)d_in[3];
    const float* attr = (const float*)d_in[4];
    const float* Wa   = (const float*)d_in[5];
    float* outp = (float*)d_out;

    char* ws = (char*)d_ws;
    int*   cnt      = (int*)ws;
    int*   tok_list = (int*)(ws + 1024);
    float* cf_list  = (float*)(ws + 1024 + (size_t)NLIST * CAPL * 4);
    float* UT       = (float*)(ws + 1024 + (size_t)2 * NLIST * CAPL * 4);
    float* aw       = UT + (size_t)NS * RDIM * HD;
    float* big      = aw + 64;                       // sc_part / y_part union
    float* sc_part  = big;
    float* y_part   = big;

    hipLaunchKernelGGL(k_prep,   dim3(NS * 8 + 1),  dim3(256), 0, stream,
                       U, attr, Wa, cnt, UT, aw);
    hipLaunchKernelGGL(k_router, dim3(BT / 64, 4),  dim3(512), 0, stream, h, Wr, sc_part);
    hipLaunchKernelGGL(k_tail,   dim3(BT / 256),    dim3(256), 0, stream,
                       sc_part, aw, cnt, tok_list, cf_list);
    hipLaunchKernelGGL(k_A,      dim3(NLIST, 2, 7), dim3(512), 0, stream,
                       h, cnt, tok_list, cf_list, UT, y_part);
    hipLaunchKernelGGL(k_B,      dim3(NS, 2, 4),    dim3(512), 0, stream,
                       V, cnt, tok_list, y_part, outp, 0);
    hipLaunchKernelGGL(k_B,      dim3(NS, 2, 4),    dim3(512), 0, stream,
                       V, cnt, tok_list, y_part, outp, 1);
}